// Round 1
// baseline (142.618 us; speedup 1.0000x reference)
//
#include <hip/hip_runtime.h>
#include <stdint.h>

// Problem constants (match reference)
constexpr int B = 4, C = 16, H = 512, W = 512;
constexpr int N = H * W;           // pixels per batch plane
constexpr float EPS = 1e-10f;

// Kernel A: per source pixel — unproject, masked transform (last channel wins),
// reproject, scatter via 64-bit atomicMax keyed by source pixel order so the
// last-write-wins (numpy) semantics are reproduced deterministically.
__global__ __launch_bounds__(256) void project_scatter_kernel(
    const float* __restrict__ depth,   // [B,1,H,W]
    const float* __restrict__ K,       // [B,3,3]
    const float* __restrict__ T,       // [B,C,4,4]
    const int*   __restrict__ masks,   // [B,C,H,W] (0/1)
    unsigned long long* __restrict__ ws) // [B,H,W] scatter keys, pre-zeroed
{
    int idx = blockIdx.x * blockDim.x + threadIdx.x;
    if (idx >= B * N) return;
    int b = idx / N;
    int n = idx - b * N;
    int v = n / W;
    int u = n - v * W;

    float d = depth[idx];

    // --- load K[b], build K_inv via adjugate (K lower row is [0,0,1]) ---
    const float* Kb = K + b * 9;
    float k00 = Kb[0], k01 = Kb[1], k02 = Kb[2];
    float k10 = Kb[3], k11 = Kb[4], k12 = Kb[5];
    float k20 = Kb[6], k21 = Kb[7], k22 = Kb[8];

    float c00 =  (k11 * k22 - k12 * k21);
    float c01 = -(k10 * k22 - k12 * k20);
    float c02 =  (k10 * k21 - k11 * k20);
    float det = k00 * c00 + k01 * c01 + k02 * c02;
    float invdet = 1.0f / det;
    // inv = adj^T / det
    float i00 =  (k11 * k22 - k12 * k21) * invdet;
    float i01 = -(k01 * k22 - k02 * k21) * invdet;
    float i02 =  (k01 * k12 - k02 * k11) * invdet;
    float i10 = -(k10 * k22 - k12 * k20) * invdet;
    float i11 =  (k00 * k22 - k02 * k20) * invdet;
    float i12 = -(k00 * k12 - k02 * k10) * invdet;
    float i20 =  (k10 * k21 - k11 * k20) * invdet;
    float i21 = -(k00 * k21 - k01 * k20) * invdet;
    float i22 =  (k00 * k11 - k01 * k10) * invdet;

    float uf = (float)u, vf = (float)v;
    // pts = (K_inv @ [u,v,1]) * depth
    float px = (i00 * uf + i01 * vf + i02) * d;
    float py = (i10 * uf + i11 * vf + i12) * d;
    float pz = (i20 * uf + i21 * vf + i22) * d;

    // --- masked per-object transform: LAST set channel wins ---
    float ox = px, oy = py, oz = pz;
    const int* mb = masks + (size_t)b * C * N + n;
    for (int c = C - 1; c >= 0; --c) {
        if (mb[(size_t)c * N] != 0) {
            const float* Tm = T + ((size_t)b * C + c) * 16;
            float tx = Tm[0]  * px + Tm[1]  * py + Tm[2]  * pz + Tm[3];
            float ty = Tm[4]  * px + Tm[5]  * py + Tm[6]  * pz + Tm[7];
            float tz = Tm[8]  * px + Tm[9]  * py + Tm[10] * pz + Tm[11];
            float tw = Tm[12] * px + Tm[13] * py + Tm[14] * pz + Tm[15];
            float denom = tw + EPS;
            ox = tx / denom;
            oy = ty / denom;
            oz = tz / denom;
            break;
        }
    }

    // --- reproject with K ---
    float qx = k00 * ox + k01 * oy + k02 * oz;
    float qy = k10 * ox + k11 * oy + k12 * oz;
    float qz = k20 * ox + k21 * oy + k22 * oz;
    float zz = qz + EPS;
    float pu = qx / zz;
    float pv = qy / zz;
    // clip then truncate (matches jnp.clip + astype(int32) for non-negative)
    pu = fminf(fmaxf(pu, 0.0f), (float)(W - 1));
    pv = fminf(fmaxf(pv, 0.0f), (float)(H - 1));
    int ui = (int)pu;
    int vi = (int)pv;

    float Z = oz;
    unsigned long long key =
        ((unsigned long long)(unsigned)(n + 1) << 32) |
        (unsigned long long)__float_as_uint(Z);
    atomicMax(&ws[(size_t)b * N + (size_t)vi * W + ui], key);
}

// Kernel B: resolve — scattered Z where a key exists, else original depth.
__global__ __launch_bounds__(256) void resolve_kernel(
    const unsigned long long* __restrict__ ws,
    const float* __restrict__ depth,
    float* __restrict__ out)
{
    int idx = blockIdx.x * blockDim.x + threadIdx.x;
    if (idx >= B * N) return;
    unsigned long long key = ws[idx];
    out[idx] = (key >> 32) ? __uint_as_float((unsigned)key) : depth[idx];
}

extern "C" void kernel_launch(void* const* d_in, const int* in_sizes, int n_in,
                              void* d_out, int out_size, void* d_ws, size_t ws_size,
                              hipStream_t stream) {
    const float* depth = (const float*)d_in[0];   // [B,1,H,W] fp32
    const float* K     = (const float*)d_in[1];   // [B,3,3]   fp32
    const float* T     = (const float*)d_in[2];   // [B,C,4,4] fp32
    const int*   masks = (const int*)d_in[3];     // [B,C,H,W] int32 0/1
    float* out = (float*)d_out;                    // [B,1,H,W] fp32

    unsigned long long* keys = (unsigned long long*)d_ws; // B*N u64 = 8 MB

    hipMemsetAsync(keys, 0, (size_t)B * N * sizeof(unsigned long long), stream);

    int total = B * N;
    int block = 256;
    int grid = (total + block - 1) / block;
    project_scatter_kernel<<<grid, block, 0, stream>>>(depth, K, T, masks, keys);
    resolve_kernel<<<grid, block, 0, stream>>>(keys, depth, out);
}

// Round 2
// 141.361 us; speedup vs baseline: 1.0089x; 1.0089x over previous
//
#include <hip/hip_runtime.h>
#include <stdint.h>

// Problem constants (match reference)
constexpr int B = 4, C = 16, H = 512, W = 512;
constexpr int N = H * W;             // pixels per batch plane (262144)
constexpr int BLOCKS_PER_BATCH = N / 256;  // 1024
constexpr float EPS = 1e-10f;

// Kernel A: per source pixel — unproject, masked transform (last channel wins),
// reproject. Stores Z per source pixel (coalesced) and scatters a u32 key
// (n+1) via atomicMax so numpy last-write-wins semantics are deterministic.
__global__ __launch_bounds__(256) void project_scatter_kernel(
    const float* __restrict__ depth,   // [B,1,H,W]
    const float* __restrict__ K,       // [B,3,3]
    const float* __restrict__ T,       // [B,C,4,4]
    const int*   __restrict__ masks,   // [B,C,H,W] (0/1)
    unsigned*    __restrict__ keys,    // [B,N] u32, pre-zeroed
    float*       __restrict__ zbuf)    // [B,N] f32
{
    int b = blockIdx.x >> 10;                        // uniform per block
    int n = ((blockIdx.x & (BLOCKS_PER_BATCH - 1)) << 8) + threadIdx.x;
    int idx = b * N + n;
    int v = n >> 9;          // n / W
    int u = n & (W - 1);     // n % W

    float d = depth[idx];

    // --- K[b] (scalar loads: b is block-uniform) ---
    const float* Kb = K + b * 9;
    float k00 = Kb[0], k01 = Kb[1], k02 = Kb[2];
    float k10 = Kb[3], k11 = Kb[4], k12 = Kb[5];
    float k20 = Kb[6], k21 = Kb[7], k22 = Kb[8];

    // adjugate inverse
    float c00 =  (k11 * k22 - k12 * k21);
    float c01 = -(k10 * k22 - k12 * k20);
    float c02 =  (k10 * k21 - k11 * k20);
    float det = k00 * c00 + k01 * c01 + k02 * c02;
    float invdet = 1.0f / det;
    float i00 =  (k11 * k22 - k12 * k21) * invdet;
    float i01 = -(k01 * k22 - k02 * k21) * invdet;
    float i02 =  (k01 * k12 - k02 * k11) * invdet;
    float i10 = -(k10 * k22 - k12 * k20) * invdet;
    float i11 =  (k00 * k22 - k02 * k20) * invdet;
    float i12 = -(k00 * k12 - k02 * k10) * invdet;
    float i20 =  (k10 * k21 - k11 * k20) * invdet;
    float i21 = -(k00 * k21 - k01 * k20) * invdet;
    float i22 =  (k00 * k11 - k01 * k10) * invdet;

    float uf = (float)u, vf = (float)v;
    float px = (i00 * uf + i01 * vf + i02) * d;
    float py = (i10 * uf + i11 * vf + i12) * d;
    float pz = (i20 * uf + i21 * vf + i22) * d;

    // --- mask scan, groups of 4 channels in parallel (highest set wins) ---
    const int* mb = masks + (size_t)b * C * N + n;
    int sel = -1;
    #pragma unroll
    for (int g = 3; g >= 0; --g) {
        int m3 = mb[(size_t)(4 * g + 3) * N];
        int m2 = mb[(size_t)(4 * g + 2) * N];
        int m1 = mb[(size_t)(4 * g + 1) * N];
        int m0 = mb[(size_t)(4 * g + 0) * N];
        int s = (m3 != 0) ? (4 * g + 3)
              : (m2 != 0) ? (4 * g + 2)
              : (m1 != 0) ? (4 * g + 1)
              : (m0 != 0) ? (4 * g + 0) : -1;
        if (s >= 0) { sel = s; break; }
    }

    float ox = px, oy = py, oz = pz;
    if (sel >= 0) {
        const float* Tm = T + ((size_t)b * C + sel) * 16;
        float tx = Tm[0]  * px + Tm[1]  * py + Tm[2]  * pz + Tm[3];
        float ty = Tm[4]  * px + Tm[5]  * py + Tm[6]  * pz + Tm[7];
        float tz = Tm[8]  * px + Tm[9]  * py + Tm[10] * pz + Tm[11];
        float tw = Tm[12] * px + Tm[13] * py + Tm[14] * pz + Tm[15];
        float denom = tw + EPS;
        ox = tx / denom;
        oy = ty / denom;
        oz = tz / denom;
    }

    // --- reproject with K ---
    float qx = k00 * ox + k01 * oy + k02 * oz;
    float qy = k10 * ox + k11 * oy + k12 * oz;
    float qz = k20 * ox + k21 * oy + k22 * oz;
    float zz = qz + EPS;
    float pu = qx / zz;
    float pv = qy / zz;
    pu = fminf(fmaxf(pu, 0.0f), (float)(W - 1));
    pv = fminf(fmaxf(pv, 0.0f), (float)(H - 1));
    int ui = (int)pu;
    int vi = (int)pv;

    zbuf[idx] = oz;                                   // coalesced plain store
    atomicMax(&keys[(size_t)b * N + (size_t)vi * W + ui], (unsigned)(n + 1));
}

// Kernel B: resolve — winner's Z where a key exists, else original depth.
__global__ __launch_bounds__(256) void resolve_kernel(
    const unsigned* __restrict__ keys,
    const float*    __restrict__ zbuf,
    const float*    __restrict__ depth,
    float*          __restrict__ out)
{
    int b = blockIdx.x >> 10;
    int n = ((blockIdx.x & (BLOCKS_PER_BATCH - 1)) << 8) + threadIdx.x;
    int idx = b * N + n;
    unsigned k = keys[idx];
    out[idx] = k ? zbuf[(size_t)b * N + (k - 1)] : depth[idx];
}

extern "C" void kernel_launch(void* const* d_in, const int* in_sizes, int n_in,
                              void* d_out, int out_size, void* d_ws, size_t ws_size,
                              hipStream_t stream) {
    const float* depth = (const float*)d_in[0];   // [B,1,H,W] fp32
    const float* K     = (const float*)d_in[1];   // [B,3,3]   fp32
    const float* T     = (const float*)d_in[2];   // [B,C,4,4] fp32
    const int*   masks = (const int*)d_in[3];     // [B,C,H,W] int32 0/1
    float* out = (float*)d_out;                    // [B,1,H,W] fp32

    unsigned* keys = (unsigned*)d_ws;                       // B*N u32 = 4 MB
    float*    zbuf = (float*)((char*)d_ws + (size_t)B * N * sizeof(unsigned)); // 4 MB

    hipMemsetAsync(keys, 0, (size_t)B * N * sizeof(unsigned), stream);

    int grid = B * BLOCKS_PER_BATCH;   // 4096 blocks of 256
    project_scatter_kernel<<<grid, 256, 0, stream>>>(depth, K, T, masks, keys, zbuf);
    resolve_kernel<<<grid, 256, 0, stream>>>(keys, zbuf, depth, out);
}